// Round 9
// baseline (3182.933 us; speedup 1.0000x reference)
//
#include <hip/hip_runtime.h>
#include <math.h>

#define LSEQ   4096
#define DMODEL 1024
#define NH     16
#define DHEAD  64
#define PSTRIDE 40  // P-buffer row stride in bf16: mult of 8 (b128 align)
// Finite mask: exp2(-30000) == 0 exactly; fully-masked half-tiles contribute
// p=0, l=0, O=0 -> trivially correct under the sum-merge (no NaN path).
#define MASKV  -30000.0f
#define C2SCALE 0.18033688f  // 0.125 * log2(e), folded into Q projection

typedef __attribute__((ext_vector_type(8))) short  bf16x8;
typedef __attribute__((ext_vector_type(4))) float  floatx4;
typedef unsigned short ushort_t;

#if __has_builtin(__builtin_amdgcn_exp2f)
#define EXP2F __builtin_amdgcn_exp2f
#else
#define EXP2F exp2f
#endif

__device__ __forceinline__ ushort_t f2bf(float x) {
  unsigned u = __builtin_bit_cast(unsigned, x);
  return (ushort_t)((u + 0x7fff + ((u >> 16) & 1)) >> 16);
}
__device__ __forceinline__ unsigned bf16pair(float a, float b) {
  return (unsigned)f2bf(a) | ((unsigned)f2bf(b) << 16);
}
// truncating pack: low16 = hi16(a), high16 = hi16(b) — 1 VALU (v_perm_b32)
__device__ __forceinline__ unsigned bfpack_trunc(float a, float b) {
  return __builtin_amdgcn_perm(__builtin_bit_cast(unsigned, b),
                               __builtin_bit_cast(unsigned, a), 0x07060302u);
}
__device__ __forceinline__ void gl_lds16(const ushort_t* g, ushort_t* l) {
  __builtin_amdgcn_global_load_lds(
      (const __attribute__((address_space(1))) void*)g,
      (__attribute__((address_space(3))) void*)l, 16, 0, 0);
}

// ---------------------------------------------------------------------------
// Exact RoPE table: rope[s][t] = {cos(s*invf_t), sin(s*invf_t)}, 4096x32.
// ---------------------------------------------------------------------------
__global__ void rope_table(float2* __restrict__ rope) {
  const int idx = blockIdx.x * 256 + threadIdx.x;  // 131072 total
  const int s = idx >> 5, t = idx & 31;
  const double invf = exp((double)t * -0.28782313662425572);  // -ln(10000)/32
  const double ang = (double)s * invf;
  rope[idx] = make_float2((float)cos(ang), (float)sin(ang));
}

// ---------------------------------------------------------------------------
// fp32 -> bf16 for [x | Wq | Wk | Wv | Wo] into one contiguous buffer.
// ---------------------------------------------------------------------------
__global__ void cvt_bf16(const float* __restrict__ x,  const float* __restrict__ wq,
                         const float* __restrict__ wk, const float* __restrict__ wv,
                         const float* __restrict__ wo, ushort_t* __restrict__ dst) {
  const size_t e = ((size_t)blockIdx.x * 256 + threadIdx.x) * 4;  // elem idx, 8M total
  const float* src; size_t off;
  if      (e < (size_t)(4u << 20)) { src = x;  off = e; }
  else if (e < (size_t)(5u << 20)) { src = wq; off = e - (size_t)(4u << 20); }
  else if (e < (size_t)(6u << 20)) { src = wk; off = e - (size_t)(5u << 20); }
  else if (e < (size_t)(7u << 20)) { src = wv; off = e - (size_t)(6u << 20); }
  else                             { src = wo; off = e - (size_t)(7u << 20); }
  const float4 v = *(const float4*)(src + off);
  uint2 p; p.x = bf16pair(v.x, v.y); p.y = bf16pair(v.z, v.w);
  *(uint2*)(dst + e) = p;
}

// ---------------------------------------------------------------------------
// m97-style bf16 MFMA GEMM (unchanged from R8).
// MODE 0: A=Om(bf16), B=Wo(bf16) -> fp32 C row-major (final projection)
// MODE 1: A=W fused QKV rows (3072xK), B=x. RoPE / V^T epilogues.
//         Q outputs are pre-scaled by C2SCALE (softmax fold).
// ---------------------------------------------------------------------------
template<int MODE>
__global__ __launch_bounds__(256)
void mfma_gemm(const ushort_t* __restrict__ A, const ushort_t* __restrict__ B,
               float* __restrict__ C, const float2* __restrict__ rope,
               ushort_t* __restrict__ Qo, ushort_t* __restrict__ Ko,
               ushort_t* __restrict__ Vo) {
  __shared__ ushort_t As[128 * 64];
  __shared__ ushort_t Bs[128 * 64];
  const int tid  = threadIdx.x;
  const int w    = tid >> 6, lane = tid & 63;
  const int wm   = w >> 1,   wn   = w & 1;
  const int quad = lane >> 4, col = lane & 15;
  const int i0 = blockIdx.x * 128;
  const int j0 = blockIdx.y * 128;

  const ushort_t* Ab = A + (size_t)i0 * DMODEL;
  const ushort_t* Bb = B + (size_t)j0 * DMODEL;

  floatx4 acc[4][4];
#pragma unroll
  for (int mt = 0; mt < 4; ++mt)
#pragma unroll
    for (int nt = 0; nt < 4; ++nt) acc[mt][nt] = (floatx4){0.f, 0.f, 0.f, 0.f};

  const int lrow = lane >> 3;
  const int lcol = (lane & 7) * 8;

  for (int k0 = 0; k0 < DMODEL; k0 += 64) {
    __syncthreads();
#pragma unroll
    for (int it = 0; it < 4; ++it) {
      const int rb = (it * 4 + w) * 8;
      gl_lds16(Ab + (size_t)(rb + lrow) * DMODEL + k0 + lcol, As + rb * 64);
      gl_lds16(Bb + (size_t)(rb + lrow) * DMODEL + k0 + lcol, Bs + rb * 64);
    }
    __syncthreads();

#pragma unroll
    for (int kk = 0; kk < 64; kk += 32) {
      bf16x8 af[4], bfr[4];
#pragma unroll
      for (int mt = 0; mt < 4; ++mt)
        af[mt] = *(const bf16x8*)(As + (wm * 64 + mt * 16 + col) * 64 + kk + quad * 8);
#pragma unroll
      for (int nt = 0; nt < 4; ++nt)
        bfr[nt] = *(const bf16x8*)(Bs + (wn * 64 + nt * 16 + col) * 64 + kk + quad * 8);
#pragma unroll
      for (int mt = 0; mt < 4; ++mt)
#pragma unroll
        for (int nt = 0; nt < 4; ++nt)
          acc[mt][nt] = __builtin_amdgcn_mfma_f32_16x16x32_bf16(
              af[mt], bfr[nt], acc[mt][nt], 0, 0, 0);
    }
  }

  if (MODE == 0) {
#pragma unroll
    for (int mt = 0; mt < 4; ++mt) {
      const int i = i0 + wm * 64 + mt * 16 + quad * 4;
#pragma unroll
      for (int nt = 0; nt < 4; ++nt) {
        const int j = j0 + wn * 64 + nt * 16 + col;
#pragma unroll
        for (int r = 0; r < 4; ++r)
          C[(size_t)(i + r) * DMODEL + j] = acc[mt][nt][r];
      }
    }
  } else {
    const int which = i0 >> 10;               // 0=Q 1=K 2=V
#pragma unroll
    for (int mt = 0; mt < 4; ++mt) {
      const int f0 = i0 + wm * 64 + mt * 16 + quad * 4;
      const int h  = (f0 >> 6) & 15;
      const int d  = f0 & 63;
      if (which == 2) {
#pragma unroll
        for (int nt = 0; nt < 4; ++nt) {
          const int s = j0 + wn * 64 + nt * 16 + col;
#pragma unroll
          for (int r = 0; r < 4; ++r)
            Vo[(size_t)(h * DHEAD + d + r) * LSEQ + s] = f2bf(acc[mt][nt][r]);
        }
      } else {
        ushort_t* dst = which ? Ko : Qo;
        const float qs = which ? 1.0f : C2SCALE;  // fold softmax scale into Q
        const int t0 = d >> 1;
#pragma unroll
        for (int nt = 0; nt < 4; ++nt) {
          const int s = j0 + wn * 64 + nt * 16 + col;
          const float4 cst = *(const float4*)((const float*)rope + ((size_t)s << 6) + t0 * 2);
          ushort_t* ob = dst + ((size_t)h * LSEQ + s) * DHEAD;
          const float x1 = acc[mt][nt][0], x2 = acc[mt][nt][1];
          const float y1 = acc[mt][nt][2], y2 = acc[mt][nt][3];
          *(unsigned*)(ob + t0)      = bf16pair((x1 * cst.x - x2 * cst.y) * qs,
                                                (y1 * cst.z - y2 * cst.w) * qs);
          *(unsigned*)(ob + t0 + 32) = bf16pair((x1 * cst.y + x2 * cst.x) * qs,
                                                (y1 * cst.w + y2 * cst.z) * qs);
        }
      }
    }
  }
}

// ---------------------------------------------------------------------------
// MFMA flash attention v7: 4 waves/SIMD + software-pipelined P round-trip.
// Grid 16 x 64 = 1024 blocks (4/CU), block 256 thr = 4 waves:
//   wave w: unit j = 2*blockIdx.y + (w&1), half = w>>1 (keys [0,32)/[32,64)
//   of each 64-key tile). All 4 waves have nkt = y+1 -> no barrier waste;
//   y-striping across the 4 co-resident blocks balances CUs.
// P pipeline: iter kt issues ds_read of P(kt-1) (ping-pong slot) BEFORE
// QK(kt)/exp2, then PV(kt-1) -> LDS latency hidden under compute; the
// write(kt)->read(kt) gap is a full iteration. vf double-buffered (2-iter
// lifetime), kf single-buffered (reloaded right after QK consumes it).
// Fixed-reference softmax (R8): no max, no rescale; l per-lane, sum-merge.
// ---------------------------------------------------------------------------
__global__ __launch_bounds__(256, 4)
void attn_mfma(const ushort_t* __restrict__ Qh, const ushort_t* __restrict__ Kh,
               const ushort_t* __restrict__ Vt, ushort_t* __restrict__ Om) {
  const int h   = blockIdx.x;
  const int y   = blockIdx.y;          // 0..63
  const int tid = threadIdx.x;
  const int w     = tid >> 6;          // 0..3
  const int upair = w & 1;             // which unit of the block's pair
  const int half  = w >> 1;            // 0 = keys [0,32), 1 = [32,64)
  const int lane = tid & 63;
  const int quad = lane >> 4;
  const int col  = lane & 15;

  const int j     = 2 * y + upair;     // q-unit 0..127
  const int qbase = j * 32;
  // diagonal 64-key tile index is y; for upair=0,half=1 it's fully masked -> skip
  int nkt = y + 1;
  if (upair == 0 && half == 1) nkt = y;

  // LDS: per-wave 2-slot P buffers (4 x 2 x 32 x PSTRIDE bf16 = 20480 B),
  // time-shared with the O-merge buffer (64 x 68 fp32 = 17408 B).
  __shared__ __align__(16) char smem[20480];
  ushort_t* Ps   = (ushort_t*)smem;
  float*    Obuf = (float*)smem;
  __shared__ float lbuf[2][2][16];
  ushort_t* psw = Ps + w * (2 * 32 * PSTRIDE);

  // Q B-frags (pre-scaled by C2), resident for the whole key loop
  bf16x8 qf[2][2];
#pragma unroll
  for (int nq = 0; nq < 2; ++nq)
#pragma unroll
    for (int c = 0; c < 2; ++c)
      qf[nq][c] = *(const bf16x8*)(Qh +
          ((size_t)(h * LSEQ + qbase + nq * 16 + col)) * DHEAD + quad * 8 + c * 32);

  floatx4 ot[4][2];
#pragma unroll
  for (int md = 0; md < 4; ++md)
#pragma unroll
    for (int nq = 0; nq < 2; ++nq) ot[md][nq] = (floatx4){0.f, 0.f, 0.f, 0.f};
  float l_[2] = {0.f, 0.f};

  bf16x8 kf[2][2], vfb[2][4], pf[2];

  auto load_k = [&](int kt) {
    const int key0 = kt * 64 + half * 32;
#pragma unroll
    for (int mk = 0; mk < 2; ++mk)
#pragma unroll
      for (int c = 0; c < 2; ++c)
        kf[mk][c] = *(const bf16x8*)(Kh +
            ((size_t)(h * LSEQ + key0 + mk * 16 + col)) * DHEAD + quad * 8 + c * 32);
  };
  auto load_v = [&](int kt, int slot) {
    const int key0 = kt * 64 + half * 32;
#pragma unroll
    for (int md = 0; md < 4; ++md)
      vfb[slot][md] = *(const bf16x8*)(Vt +
          ((size_t)(h * DHEAD + md * 16 + col)) * LSEQ + key0 + quad * 8);
  };

  if (nkt > 0) {
    load_k(0);
    load_v(0, 0);

    for (int kt = 0; kt < nkt; ++kt) {
      // (1) issue ds_read of P(kt-1) early — latency hides under QK+exp2
      if (kt > 0) {
        ushort_t* rs = psw + ((kt - 1) & 1) * (32 * PSTRIDE);
#pragma unroll
        for (int nq = 0; nq < 2; ++nq)
          pf[nq] = *(const bf16x8*)(rs + (nq * 16 + col) * PSTRIDE + quad * 8);
      }

      // (2) S^T = K . (C2*Q)^T for tile kt
      floatx4 st[2][2];
#pragma unroll
      for (int mk = 0; mk < 2; ++mk)
#pragma unroll
        for (int nq = 0; nq < 2; ++nq) st[mk][nq] = (floatx4){0.f, 0.f, 0.f, 0.f};
#pragma unroll
      for (int mk = 0; mk < 2; ++mk)
#pragma unroll
        for (int c = 0; c < 2; ++c)
#pragma unroll
          for (int nq = 0; nq < 2; ++nq)
            st[mk][nq] = __builtin_amdgcn_mfma_f32_16x16x32_bf16(
                kf[mk][c], qf[nq][c], st[mk][nq], 0, 0, 0);

      // (3) reload kf for kt+1 (kf consumed by QK above)
      if (kt + 1 < nkt) load_k(kt + 1);

      // (4) diagonal mask (true diagonal tile is kt == y)
      if (kt == y) {
        const int key0 = kt * 64 + half * 32;
#pragma unroll
        for (int mk = 0; mk < 2; ++mk) {
          const int keyb = key0 + mk * 16 + quad * 4;
#pragma unroll
          for (int nq = 0; nq < 2; ++nq) {
            const int q = qbase + nq * 16 + col;
#pragma unroll
            for (int r = 0; r < 4; ++r)
              if (keyb + r > q) st[mk][nq][r] = MASKV;
          }
        }
      }

      // (5) p = exp2(S); accumulate l
#pragma unroll
      for (int mk = 0; mk < 2; ++mk)
#pragma unroll
        for (int nq = 0; nq < 2; ++nq) {
#pragma unroll
          for (int r = 0; r < 4; ++r) st[mk][nq][r] = EXP2F(st[mk][nq][r]);
          l_[nq] += (st[mk][nq][0] + st[mk][nq][1]) + (st[mk][nq][2] + st[mk][nq][3]);
        }

      // (6) PV(kt-1): pf ready by now; vf from slot (kt-1)&1
      if (kt > 0) {
#pragma unroll
        for (int md = 0; md < 4; ++md)
#pragma unroll
          for (int nq = 0; nq < 2; ++nq)
            ot[md][nq] = __builtin_amdgcn_mfma_f32_16x16x32_bf16(
                vfb[(kt - 1) & 1][md], pf[nq], ot[md][nq], 0, 0, 0);
      }

      // (7) P(kt) -> LDS slot kt&1 (read next iteration)
      {
        ushort_t* ws = psw + (kt & 1) * (32 * PSTRIDE);
#pragma unroll
        for (int mk = 0; mk < 2; ++mk)
#pragma unroll
          for (int nq = 0; nq < 2; ++nq) {
            uint2 pk;
            pk.x = bfpack_trunc(st[mk][nq][0], st[mk][nq][1]);
            pk.y = bfpack_trunc(st[mk][nq][2], st[mk][nq][3]);
            *(uint2*)(ws + (nq * 16 + col) * PSTRIDE + mk * 16 + quad * 4) = pk;
          }
      }

      // (8) V for kt+1 into slot (kt+1)&1 (slot (kt-1)&1 just consumed)
      if (kt + 1 < nkt) load_v(kt + 1, (kt + 1) & 1);
    }

    // flush PV(nkt-1)
    {
      ushort_t* rs = psw + ((nkt - 1) & 1) * (32 * PSTRIDE);
#pragma unroll
      for (int nq = 0; nq < 2; ++nq)
        pf[nq] = *(const bf16x8*)(rs + (nq * 16 + col) * PSTRIDE + quad * 8);
#pragma unroll
      for (int md = 0; md < 4; ++md)
#pragma unroll
        for (int nq = 0; nq < 2; ++nq)
          ot[md][nq] = __builtin_amdgcn_mfma_f32_16x16x32_bf16(
              vfb[(nkt - 1) & 1][md], pf[nq], ot[md][nq], 0, 0, 0);
    }
  }

  // l reduction (only cross-lane ops in the kernel)
#pragma unroll
  for (int nq = 0; nq < 2; ++nq) {
    float ls = l_[nq];
    ls += __shfl_xor(ls, 16);
    ls += __shfl_xor(ls, 32);
    l_[nq] = ls;
  }

  __syncthreads();  // key loops done; P region free for merge reuse

  if (half == 1) {  // upper-half wave dumps partials
#pragma unroll
    for (int nq = 0; nq < 2; ++nq) {
      if (quad == 0) lbuf[upair][nq][col] = l_[nq];
#pragma unroll
      for (int md = 0; md < 4; ++md)
        *(float4*)(Obuf + ((upair * 2 + nq) * 16 + col) * 68 + md * 16 + quad * 4) =
            (float4){ot[md][nq][0], ot[md][nq][1], ot[md][nq][2], ot[md][nq][3]};
    }
  }
  __syncthreads();

  if (half == 0) {  // lower-half wave merges (plain sums) and writes Om
#pragma unroll
    for (int nq = 0; nq < 2; ++nq) {
      const float inv = 1.0f / (l_[nq] + lbuf[upair][nq][col]);
      const int q = qbase + nq * 16 + col;
#pragma unroll
      for (int md = 0; md < 4; ++md) {
        const float4 ob =
            *(const float4*)(Obuf + ((upair * 2 + nq) * 16 + col) * 68 + md * 16 + quad * 4);
        uint2 pk;
        pk.x = bf16pair((ot[md][nq][0] + ob.x) * inv, (ot[md][nq][1] + ob.y) * inv);
        pk.y = bf16pair((ot[md][nq][2] + ob.z) * inv, (ot[md][nq][3] + ob.w) * inv);
        *(uint2*)(Om + (size_t)q * DMODEL + h * DHEAD + md * 16 + quad * 4) = pk;
      }
    }
  }
}

extern "C" void kernel_launch(void* const* d_in, const int* in_sizes, int n_in,
                              void* d_out, int out_size, void* d_ws, size_t ws_size,
                              hipStream_t stream) {
  const float* x  = (const float*)d_in[0];
  const float* Wq = (const float*)d_in[2];
  const float* Wk = (const float*)d_in[3];
  const float* Wv = (const float*)d_in[4];
  const float* Wo = (const float*)d_in[5];
  float* out = (float*)d_out;

  const size_t M1 = (size_t)1 << 20;
  ushort_t* xb  = (ushort_t*)d_ws;      // bf16 x          4M elems
  ushort_t* Wb  = xb  + 4 * M1;         // bf16 Wq|Wk|Wv   3M (contiguous)
  ushort_t* wob = Wb  + 3 * M1;         // bf16 Wo         1M
  ushort_t* Qh  = wob + 1 * M1;         // bf16 [H][L][DH] 4M (pre-scaled C2)
  ushort_t* Kh  = Qh  + 4 * M1;         // bf16 [H][L][DH] 4M
  ushort_t* Vt  = Kh  + 4 * M1;         // bf16 [H][DH][L] 4M
  ushort_t* Om  = Vt  + 4 * M1;         // bf16 [L][D]     4M
  float2*   rope = (float2*)(Om + 4 * M1);  // 4096x32 float2, 1 MB

  rope_table<<<512, 256, 0, stream>>>(rope);
  cvt_bf16<<<8192, 256, 0, stream>>>(x, Wq, Wk, Wv, Wo, xb);
  mfma_gemm<1><<<dim3(3072 / 128, LSEQ / 128), 256, 0, stream>>>(
      Wb, xb, nullptr, rope, Qh, Kh, Vt);
  attn_mfma<<<dim3(NH, 64), 256, 0, stream>>>(Qh, Kh, Vt, Om);
  mfma_gemm<0><<<dim3(LSEQ / 128, DMODEL / 128), 256, 0, stream>>>(
      Om, wob, out, nullptr, nullptr, nullptr, nullptr);
}